// Round 14
// baseline (308.903 us; speedup 1.0000x reference)
//
#include <hip/hip_runtime.h>
#include <hip/hip_bf16.h>

#define NB 4096
#define MB 1024
#define SZ ((size_t)MB * NB)
#define NN ((size_t)NB * NB)

typedef __bf16 bf16_t;
typedef __attribute__((ext_vector_type(8))) __bf16 bf16x8;
typedef __attribute__((ext_vector_type(4))) float f32x4;
typedef __attribute__((ext_vector_type(16))) float f32x16;
typedef __attribute__((ext_vector_type(4))) unsigned int u32x4;

#define AS1 __attribute__((address_space(1)))
#define AS3 __attribute__((address_space(3)))
#define GLOAD16(gp, lp)                                                        \
  __builtin_amdgcn_global_load_lds((const AS1 unsigned int*)(gp),              \
                                   (AS3 unsigned int*)(lp), 16, 0, 0)
#define SBAR() __builtin_amdgcn_s_barrier()
#define SCHEDB() __builtin_amdgcn_sched_barrier(0)
#define MFMA16(a, b, c) __builtin_amdgcn_mfma_f32_16x16x32_bf16((a), (b), (c), 0, 0, 0)
#define MFMA32(a, b, c) __builtin_amdgcn_mfma_f32_32x32x16_bf16((a), (b), (c), 0, 0, 0)
#define VMCNT(n) asm volatile("s_waitcnt vmcnt(" #n ")" ::: "memory")

// Half-K LDS layout (verified 0-conflict r7): [rows][32 k] bf16, cells of
// 8 bf16; cell (r,c) at slot c ^ ((r>>1)&3). gload_lds writes linearly
// (cell t -> row t>>2, slot t&3); global source chunk (t&3)^((t>>3)&3).
// Sync (v6, verified best): ring-4 slots, prefetch distance 3, steady
// vmcnt(8) (2 halves in flight), one barrier per half, tail 4->0.
// r14: MFMA shape 32x32x16 (2495 vs 2075 TF ubench) — operands:
//   A/B: dim = lane&31, k-chunk = (lane>>5)*8 (same convention as our
//   verified 16x16 usage with lane&15 / lane>>4).
//   C/D (m74/m101): col = lane&31, row = (reg&3)+8*(reg>>2)+4*(lane>>5).

__device__ __forceinline__ bf16x8 neg8(bf16x8 x) {
  u32x4 t;
  __builtin_memcpy(&t, &x, 16);
  t ^= 0x80008000u;
  bf16x8 y;
  __builtin_memcpy(&y, &t, 16);
  return y;
}

__device__ __forceinline__ bf16x8 cvt8(float4 a, float4 b) {
  bf16x8 v;
  v[0] = (bf16_t)a.x; v[1] = (bf16_t)a.y; v[2] = (bf16_t)a.z; v[3] = (bf16_t)a.w;
  v[4] = (bf16_t)b.x; v[5] = (bf16_t)b.y; v[6] = (bf16_t)b.z; v[7] = (bf16_t)b.w;
  return v;
}

// ---------------- prep: f32 -> bf16 ----------------
#define ITEM_S (SZ / 8)
#define ITEM_N (NN / 8)

__global__ __launch_bounds__(256) void prep6_kernel(
    const float* __restrict__ u, const float* __restrict__ w,
    const float* __restrict__ G, const float* __restrict__ Bm,
    const float* __restrict__ Wp, const float* __restrict__ Wq,
    bf16_t* __restrict__ ws) {
  size_t stride = (size_t)gridDim.x * blockDim.x;
  const size_t tot = 2 * ITEM_S + 4 * ITEM_N;
  for (size_t i = (size_t)blockIdx.x * blockDim.x + threadIdx.x; i < tot;
       i += stride) {
    const float* src;
    bf16_t* dst;
    size_t off;
    if (i < ITEM_S) { src = u; dst = ws; off = i; }
    else if (i < 2 * ITEM_S) { src = w; dst = ws + SZ; off = i - ITEM_S; }
    else if (i < 2 * ITEM_S + ITEM_N) { src = G; dst = ws + 2 * SZ; off = i - 2 * ITEM_S; }
    else if (i < 2 * ITEM_S + 2 * ITEM_N) { src = Bm; dst = ws + 2 * SZ + NN; off = i - 2 * ITEM_S - ITEM_N; }
    else if (i < 2 * ITEM_S + 3 * ITEM_N) { src = Wp; dst = ws + 2 * SZ + 2 * NN; off = i - 2 * ITEM_S - 2 * ITEM_N; }
    else { src = Wq; dst = ws + 2 * SZ + 3 * NN; off = i - 2 * ITEM_S - 3 * ITEM_N; }
    const float4* s = reinterpret_cast<const float4*>(src) + off * 2;
    reinterpret_cast<bf16x8*>(dst)[off] = cvt8(s[0], s[1]);
  }
}

__global__ __launch_bounds__(256) void prep4_kernel(
    const float* __restrict__ u, const float* __restrict__ w,
    const float* __restrict__ G, const float* __restrict__ Bm,
    bf16_t* __restrict__ ws) {
  size_t stride = (size_t)gridDim.x * blockDim.x;
  const size_t tot = 2 * ITEM_S + 2 * ITEM_N;
  for (size_t i = (size_t)blockIdx.x * blockDim.x + threadIdx.x; i < tot;
       i += stride) {
    const float* src;
    bf16_t* dst;
    size_t off;
    if (i < ITEM_S) { src = u; dst = ws; off = i; }
    else if (i < 2 * ITEM_S) { src = w; dst = ws + SZ; off = i - ITEM_S; }
    else if (i < 2 * ITEM_S + ITEM_N) { src = G; dst = ws + 2 * SZ; off = i - 2 * ITEM_S; }
    else { src = Bm; dst = ws + 2 * SZ + NN; off = i - 2 * ITEM_S - ITEM_N; }
    const float4* s = reinterpret_cast<const float4*>(src) + off * 2;
    reinterpret_cast<bf16x8*>(dst)[off] = cvt8(s[0], s[1]);
  }
}

// ---------------- fused stage 1: v6 structure + 32x32x16 MFMA --------------
// S = u@G^T - w@B^T, T = w@G^T + u@B^T; p_mid/q_mid epilogue (bf16).
// Tile 128x128, 8 waves (2m x 4n, wave 64x32 via 2 m-frags of 32), ring-4
// (128 KB). Per wave per half: 12 ds_read + 4 gload_lds + 16 MFMA(32x32x16).
__global__ __launch_bounds__(512, 2) void fused1_v11(
    const float* __restrict__ u, const float* __restrict__ w,
    const bf16_t* __restrict__ ubf, const bf16_t* __restrict__ wbf,
    const bf16_t* __restrict__ Gbf, const bf16_t* __restrict__ Bbf,
    const float* __restrict__ bias_p, const float* __restrict__ bias_q,
    bf16_t* __restrict__ pq) {
  __shared__ bf16_t lds[4][4][128 * 32];  // [slot][op][row*32] = 128 KB
  const int tid = threadIdx.x, lane = tid & 63, wv = tid >> 6;
  const int bid = blockIdx.x;
  const int t = (bid & 7) * 32 + (bid >> 3);  // XCD swizzle, 256 blocks
  const int row0 = (t & 7) * 128, col0 = (t >> 3) * 128;
  const int wm = (wv >> 2) * 64, wn = (wv & 3) * 32;
  const int lr32 = lane & 31, hi = lane >> 5;
  const int sw = (lr32 >> 1) & 3;

  // staging identical to v6: 1 cell/thread/op per half
  const int srow = wv * 16 + (lane >> 2);
  const int sc = (lane & 3) ^ ((lane >> 3) & 3);
  const bf16_t* gsrc[4];
  gsrc[0] = ubf + (size_t)(row0 + srow) * NB + sc * 8;
  gsrc[1] = wbf + (size_t)(row0 + srow) * NB + sc * 8;
  gsrc[2] = Gbf + (size_t)(col0 + srow) * NB + sc * 8;
  gsrc[3] = Bbf + (size_t)(col0 + srow) * NB + sc * 8;

#define F1_ISS(op, sl, ko) GLOAD16(gsrc[op] + (ko), &lds[sl][op][wv * 512])

  // frag read offsets: A rows wm+mi*32+lr32, B rows wn+lr32;
  // k-chunk for k16 kk: (kk*2 + hi) ^ sw  (bank-uniform, same family as r7)
  int kchunk[2];
#pragma unroll
  for (int kk = 0; kk < 2; ++kk) kchunk[kk] = (((kk * 2 + hi) ^ sw) << 3);
  int aoff[2];
#pragma unroll
  for (int mi = 0; mi < 2; ++mi) aoff[mi] = (wm + mi * 32 + lr32) * 32;
  const int boff = (wn + lr32) * 32;

  f32x16 aS[2] = {}, aT[2] = {};

  // prologue: issue halves 0,1,2 (v6 sync)
#pragma unroll
  for (int hh = 0; hh < 3; ++hh) {
    F1_ISS(0, hh, hh * 32);
    F1_ISS(1, hh, hh * 32);
    F1_ISS(2, hh, hh * 32);
    F1_ISS(3, hh, hh * 32);
  }
  VMCNT(8);
  SBAR();
  SCHEDB();

  const int HTOT = 128;
  for (int h = 0; h < HTOT; ++h) {
    const int slot = h & 3;
    const bool pf = (h + 3) < HTOT;
    const int pslot = (h + 3) & 3;
    const int pko = (h + 3) * 32;

    bf16x8 bG[2], bB[2], au[2][2], aw[2][2];
#pragma unroll
    for (int kk = 0; kk < 2; ++kk) {
      bG[kk] = *reinterpret_cast<const bf16x8*>(&lds[slot][2][boff + kchunk[kk]]);
      bB[kk] = *reinterpret_cast<const bf16x8*>(&lds[slot][3][boff + kchunk[kk]]);
#pragma unroll
      for (int mi = 0; mi < 2; ++mi) {
        au[mi][kk] = *reinterpret_cast<const bf16x8*>(&lds[slot][0][aoff[mi] + kchunk[kk]]);
        aw[mi][kk] = *reinterpret_cast<const bf16x8*>(&lds[slot][1][aoff[mi] + kchunk[kk]]);
      }
    }
    if (pf) {
      F1_ISS(0, pslot, pko);
      F1_ISS(1, pslot, pko);
      F1_ISS(2, pslot, pko);
      F1_ISS(3, pslot, pko);
    }
#pragma unroll
    for (int kk = 0; kk < 2; ++kk) {
      bf16x8 bn = neg8(bB[kk]);
#pragma unroll
      for (int mi = 0; mi < 2; ++mi) {
        aS[mi] = MFMA32(au[mi][kk], bG[kk], aS[mi]);
        aS[mi] = MFMA32(aw[mi][kk], bn, aS[mi]);
        aT[mi] = MFMA32(aw[mi][kk], bG[kk], aT[mi]);
        aT[mi] = MFMA32(au[mi][kk], bB[kk], aT[mi]);
      }
    }
    // v6 counted sync per half
    if (h < HTOT - 3)
      VMCNT(8);
    else if (h == HTOT - 3)
      VMCNT(4);
    else if (h == HTOT - 2)
      VMCNT(0);
    SBAR();
    SCHEDB();
  }

  // epilogue: 32x32 C/D layout: col=lane&31, row=(j&3)+8*(j>>2)+4*hi
  const int c = col0 + wn + lr32;
  const float bp_ = bias_p[c], bq_ = bias_q[c];
#pragma unroll
  for (int mi = 0; mi < 2; ++mi) {
#pragma unroll
    for (int j = 0; j < 16; ++j) {
      int r = row0 + wm + mi * 32 + (j & 3) + 8 * (j >> 2) + 4 * hi;
      size_t idx = (size_t)r * NB + c;
      float U = u[idx], W = w[idx];
      float S = aS[mi][j], T = aT[mi][j];
      pq[idx] = (bf16_t)(U * S + W * T + bp_);
      pq[SZ + idx] = (bf16_t)(W * S - U * T + bq_);
    }
  }
}

// ---------------- stage 2: flat ring-4, 2 blocks/CU (best gemm2) -----------
__global__ __launch_bounds__(256, 2) void gemm2_v9(
    const bf16_t* __restrict__ pq, const bf16_t* __restrict__ Wpb,
    const bf16_t* __restrict__ Wqb, const float* __restrict__ bp,
    const float* __restrict__ bq, float* __restrict__ out) {
  __shared__ bf16_t lds[4][2][128 * 32];  // [slot][A/W] = 64 KB
  const int tid = threadIdx.x, lane = tid & 63, wv = tid >> 6;
  const int bid = blockIdx.x;
  const int t = (bid & 7) * 64 + (bid >> 3);  // XCD swizzle, 512 blocks
  const int z = t >> 8;
  const int s = t & 255;
  const int row0 = (s & 7) * 128, col0 = (s >> 3) * 128;
  const int koff = (bid & 1) << 6;

  const bf16_t* A = pq + (size_t)z * SZ;
  const bf16_t* Wm = z ? Wqb : Wpb;
  const float* bias = z ? bq : bp;
  float* C = out + (size_t)z * SZ;

  const int wm = (wv >> 1) * 64, wn = (wv & 1) * 64;
  const int lr = lane & 15, kq = lane >> 4;
  const int kswz = (kq ^ ((lr >> 1) & 3)) << 3;

  const int srow = tid >> 2;  // 0..63
  const int sc = (tid & 3) ^ ((tid >> 3) & 3);
  const bf16_t* gA0 = A + (size_t)(row0 + srow) * NB + sc * 8;
  const bf16_t* gA1 = gA0 + (size_t)64 * NB;
  const bf16_t* gW0 = Wm + (size_t)(col0 + srow) * NB + sc * 8;
  const bf16_t* gW1 = gW0 + (size_t)64 * NB;

#define G2_ISSUE(hh)                                                           \
  do {                                                                         \
    const int _sl = (hh) & 3;                                                  \
    const int _ko = (((hh) + koff) & 127) * 32;                                \
    GLOAD16(gA0 + _ko, &lds[_sl][0][wv * 512]);                                \
    GLOAD16(gA1 + _ko, &lds[_sl][0][2048 + wv * 512]);                         \
    GLOAD16(gW0 + _ko, &lds[_sl][1][wv * 512]);                                \
    GLOAD16(gW1 + _ko, &lds[_sl][1][2048 + wv * 512]);                         \
  } while (0)

  int aoff[4], woff[4];
#pragma unroll
  for (int m = 0; m < 4; ++m) aoff[m] = (wm + m * 16 + lr) * 32 + kswz;
#pragma unroll
  for (int n = 0; n < 4; ++n) woff[n] = (wn + n * 16 + lr) * 32 + kswz;

  f32x4 acc[4][4] = {};

  G2_ISSUE(0); G2_ISSUE(1); G2_ISSUE(2);
  VMCNT(4);
  SBAR();
  SCHEDB();

  const int HTOT = 2 * (NB / 64);
  for (int h = 0; h < HTOT; ++h) {
    const int slot = h & 3;
    const bool pf = (h + 3) < HTOT;

    bf16x8 av[4], bw[4];
#pragma unroll
    for (int m = 0; m < 4; ++m)
      av[m] = *reinterpret_cast<const bf16x8*>(&lds[slot][0][aoff[m]]);
#pragma unroll
    for (int n = 0; n < 4; ++n)
      bw[n] = *reinterpret_cast<const bf16x8*>(&lds[slot][1][woff[n]]);
    if (pf) G2_ISSUE(h + 3);
#pragma unroll
    for (int m = 0; m < 4; ++m)
#pragma unroll
      for (int n = 0; n < 4; ++n)
        acc[m][n] = MFMA16(av[m], bw[n], acc[m][n]);
    if (h < HTOT - 3)
      VMCNT(4);
    else if (h == HTOT - 3)
      VMCNT(2);
    else if (h == HTOT - 2)
      VMCNT(0);
    SBAR();
    SCHEDB();
  }

  const int fr = lane & 15, fq = kq;
#pragma unroll
  for (int m = 0; m < 4; ++m)
#pragma unroll
    for (int n = 0; n < 4; ++n)
#pragma unroll
      for (int j = 0; j < 4; ++j) {
        int r = row0 + wm + m * 16 + fq * 4 + j;
        int c = col0 + wn + n * 16 + fr;
        C[(size_t)r * NB + c] = acc[m][n][j] + bias[c];
      }
}

// ---------------- fallbacks (compile-only safety net) ----------------
__device__ __forceinline__ int swz_off32(int r, int kk) {
  return r * 32 + ((kk ^ ((r >> 1) & 3)) << 3);
}

__device__ __forceinline__ void fb_stage_f32(const float* __restrict__ src,
                                             int row0, int k0, bf16_t* lds, int t) {
  int r = t >> 2, kk = t & 3;
  const float* p = src + (size_t)(row0 + r) * NB + k0 + (kk << 3);
  float4 v0 = *reinterpret_cast<const float4*>(p);
  float4 v1 = *reinterpret_cast<const float4*>(p + 4);
  *reinterpret_cast<bf16x8*>(lds + swz_off32(r, kk)) = cvt8(v0, v1);
}

__global__ __launch_bounds__(256, 2) void fb_gemm2(
    const bf16_t* __restrict__ pq, const float* __restrict__ Wp,
    const float* __restrict__ Wq, const float* __restrict__ bp,
    const float* __restrict__ bq, float* __restrict__ out) {
  __shared__ bf16_t lA[128 * 32], lW[128 * 32];
  const int z = blockIdx.z;
  const bf16_t* A = pq + (size_t)z * SZ;
  const float* Wm = z ? Wq : Wp;
  const float* bias = z ? bq : bp;
  float* C = out + (size_t)z * SZ;
  const int tid = threadIdx.x;
  const int lane = tid & 63, wv = tid >> 6;
  const int wm = (wv >> 1) * 64, wn = (wv & 1) * 64;
  const int row0 = blockIdx.y * 128, col0 = blockIdx.x * 128;
  const int lr = lane & 15, kq = lane >> 4;
  const int fslot = (kq ^ ((lr >> 1) & 3)) << 3;
  f32x4 acc[4][4] = {};
  for (int kt = 0; kt < NB; kt += 32) {
#pragma unroll
    for (int p = 0; p < 2; ++p) {
      int cb = p * 256 + wv * 64;
      int ci = cb + lane;
      int r = ci >> 2, kl = ci & 3;
      int ks = kl ^ ((r >> 1) & 3);
      const bf16_t* g = A + (size_t)(row0 + r) * NB + kt + (ks << 3);
      GLOAD16(g, lA + cb * 8);
    }
#pragma unroll
    for (int p = 0; p < 2; ++p)
      fb_stage_f32(Wm, col0, kt, lW, p * 256 + tid);
    __syncthreads();
    bf16x8 af[4], bg[4];
#pragma unroll
    for (int m = 0; m < 4; ++m)
      af[m] = *reinterpret_cast<const bf16x8*>(lA + (wm + m * 16 + lr) * 32 + fslot);
#pragma unroll
    for (int n = 0; n < 4; ++n)
      bg[n] = *reinterpret_cast<const bf16x8*>(lW + (wn + n * 16 + lr) * 32 + fslot);
#pragma unroll
    for (int m = 0; m < 4; ++m)
#pragma unroll
      for (int n = 0; n < 4; ++n)
        acc[m][n] = MFMA16(af[m], bg[n], acc[m][n]);
    __syncthreads();
  }
  const int fr = lane & 15, fq = lane >> 4;
#pragma unroll
  for (int m = 0; m < 4; ++m)
#pragma unroll
    for (int n = 0; n < 4; ++n)
#pragma unroll
      for (int j = 0; j < 4; ++j) {
        int r = row0 + wm + m * 16 + fq * 4 + j;
        int c = col0 + wn + n * 16 + fr;
        C[(size_t)r * NB + c] = acc[m][n][j] + bias[c];
      }
}

__global__ __launch_bounds__(512, 2) void fb_fused1(
    const float* __restrict__ u, const float* __restrict__ w,
    const float* __restrict__ G, const float* __restrict__ Bm,
    const float* __restrict__ bias_p, const float* __restrict__ bias_q,
    bf16_t* __restrict__ pq) {
  __shared__ bf16_t lU[128 * 32], lW[128 * 32], lG[128 * 32], lB[128 * 32];
  const int tid = threadIdx.x;
  const int lane = tid & 63, wv = tid >> 6;
  const int wm = (wv >> 2) * 64, wn = (wv & 3) * 32;
  const int row0 = blockIdx.y * 128, col0 = blockIdx.x * 128;
  const int lr = lane & 15, kq = lane >> 4;
  const int fslot = (kq ^ ((lr >> 1) & 3)) << 3;
  f32x4 aS[4][2] = {}, aT[4][2] = {};
  for (int kt = 0; kt < NB; kt += 32) {
    fb_stage_f32(u, row0, kt, lU, tid);
    fb_stage_f32(w, row0, kt, lW, tid);
    fb_stage_f32(G, col0, kt, lG, tid);
    fb_stage_f32(Bm, col0, kt, lB, tid);
    __syncthreads();
    bf16x8 au[4], aw[4], bG[2], bB[2], bBn[2];
#pragma unroll
    for (int m = 0; m < 4; ++m) {
      int off = (wm + m * 16 + lr) * 32 + fslot;
      au[m] = *reinterpret_cast<const bf16x8*>(lU + off);
      aw[m] = *reinterpret_cast<const bf16x8*>(lW + off);
    }
#pragma unroll
    for (int n = 0; n < 2; ++n) {
      int off = (wn + n * 16 + lr) * 32 + fslot;
      bG[n] = *reinterpret_cast<const bf16x8*>(lG + off);
      bB[n] = *reinterpret_cast<const bf16x8*>(lB + off);
      bBn[n] = neg8(bB[n]);
    }
#pragma unroll
    for (int m = 0; m < 4; ++m)
#pragma unroll
      for (int n = 0; n < 2; ++n) {
        aS[m][n] = MFMA16(au[m], bG[n], aS[m][n]);
        aS[m][n] = MFMA16(aw[m], bBn[n], aS[m][n]);
        aT[m][n] = MFMA16(aw[m], bG[n], aT[m][n]);
        aT[m][n] = MFMA16(au[m], bB[n], aT[m][n]);
      }
    __syncthreads();
  }
  const int fr = lane & 15, fq = lane >> 4;
#pragma unroll
  for (int m = 0; m < 4; ++m)
#pragma unroll
    for (int n = 0; n < 2; ++n)
#pragma unroll
      for (int j = 0; j < 4; ++j) {
        int r = row0 + wm + m * 16 + fq * 4 + j;
        int c = col0 + wn + n * 16 + fr;
        size_t idx = (size_t)r * NB + c;
        float U = u[idx], W = w[idx];
        float S = aS[m][n][j], T = aT[m][n][j];
        pq[idx] = (bf16_t)(U * S + W * T + bias_p[c]);
        pq[SZ + idx] = (bf16_t)(W * S - U * T + bias_q[c]);
      }
}

extern "C" void kernel_launch(void* const* d_in, const int* in_sizes, int n_in,
                              void* d_out, int out_size, void* d_ws, size_t ws_size,
                              hipStream_t stream) {
  const float* u = (const float*)d_in[0];
  const float* w = (const float*)d_in[1];
  const float* G = (const float*)d_in[2];
  const float* Bm = (const float*)d_in[3];
  const float* bias_p = (const float*)d_in[4];
  const float* bias_q = (const float*)d_in[5];
  const float* Wp = (const float*)d_in[6];
  const float* bp = (const float*)d_in[7];
  const float* Wq = (const float*)d_in[8];
  const float* bq = (const float*)d_in[9];
  (void)in_sizes; (void)n_in; (void)out_size;

  const size_t need_full = (6 * SZ + 4 * NN) * sizeof(bf16_t);  // 176 MB
  const size_t need_mid = (6 * SZ + 2 * NN) * sizeof(bf16_t);   // 112 MB

  if (ws_size >= need_full) {
    bf16_t* ws = (bf16_t*)d_ws;
    bf16_t* ubf = ws;
    bf16_t* wbf = ws + SZ;
    bf16_t* Gbf = ws + 2 * SZ;
    bf16_t* Bbf = Gbf + NN;
    bf16_t* Wpb = Bbf + NN;
    bf16_t* Wqb = Wpb + NN;
    bf16_t* pqw = Wqb + NN;
    prep6_kernel<<<2048, 256, 0, stream>>>(u, w, G, Bm, Wp, Wq, ws);
    fused1_v11<<<256, 512, 0, stream>>>(u, w, ubf, wbf, Gbf, Bbf,
                                        bias_p, bias_q, pqw);
    gemm2_v9<<<512, 256, 0, stream>>>(pqw, Wpb, Wqb, bp, bq, (float*)d_out);
  } else if (ws_size >= need_mid) {
    bf16_t* ws = (bf16_t*)d_ws;
    bf16_t* ubf = ws;
    bf16_t* wbf = ws + SZ;
    bf16_t* Gbf = ws + 2 * SZ;
    bf16_t* Bbf = Gbf + NN;
    bf16_t* pqw = Bbf + NN;
    prep4_kernel<<<2048, 256, 0, stream>>>(u, w, G, Bm, ws);
    fused1_v11<<<256, 512, 0, stream>>>(u, w, ubf, wbf, Gbf, Bbf,
                                        bias_p, bias_q, pqw);
    fb_gemm2<<<dim3(NB / 128, MB / 128, 2), 256, 0, stream>>>(
        pqw, Wp, Wq, bp, bq, (float*)d_out);
  } else {
    bf16_t* pqw = (bf16_t*)d_ws;
    fb_fused1<<<dim3(NB / 128, MB / 128), 512, 0, stream>>>(
        u, w, G, Bm, bias_p, bias_q, pqw);
    fb_gemm2<<<dim3(NB / 128, MB / 128, 2), 256, 0, stream>>>(
        pqw, Wp, Wq, bp, bq, (float*)d_out);
  }
}

// Round 15
// 301.400 us; speedup vs baseline: 1.0249x; 1.0249x over previous
//
#include <hip/hip_runtime.h>
#include <hip/hip_bf16.h>

#define NB 4096
#define MB 1024
#define SZ ((size_t)MB * NB)
#define NN ((size_t)NB * NB)

typedef __bf16 bf16_t;
typedef __attribute__((ext_vector_type(8))) __bf16 bf16x8;
typedef __attribute__((ext_vector_type(4))) float f32x4;
typedef __attribute__((ext_vector_type(4))) unsigned int u32x4;

#define AS1 __attribute__((address_space(1)))
#define AS3 __attribute__((address_space(3)))
#define GLOAD16(gp, lp)                                                        \
  __builtin_amdgcn_global_load_lds((const AS1 unsigned int*)(gp),              \
                                   (AS3 unsigned int*)(lp), 16, 0, 0)
#define SBAR() __builtin_amdgcn_s_barrier()
#define SCHEDB() __builtin_amdgcn_sched_barrier(0)
#define MFMA16(a, b, c) __builtin_amdgcn_mfma_f32_16x16x32_bf16((a), (b), (c), 0, 0, 0)
#define VMCNT(n) asm volatile("s_waitcnt vmcnt(" #n ")" ::: "memory")

// Half-K LDS layout (verified 0-conflict r7/r8): [rows][32 k] bf16, cells of
// 8 bf16; cell (r,c) at slot c ^ ((r>>1)&3). gload_lds writes linearly
// (cell t -> row t>>2, slot t&3); global source chunk (t&3)^((t>>3)&3).
// Reads use 16-row groups (rows 16a + (lane&15), chunk keyed on lane>>4) —
// the ONLY pattern measured conflict-free (r7/r8); 32-row-span reads (r14)
// re-introduced 1.26e7 conflict cycles.
// Sync (v6, ledger best 133.7us): ring-4 slots, prefetch distance 3, steady
// vmcnt(8) (2 halves in flight), one barrier per half, tail 4 -> 0.

__device__ __forceinline__ bf16x8 neg8(bf16x8 x) {
  u32x4 t;
  __builtin_memcpy(&t, &x, 16);
  t ^= 0x80008000u;
  bf16x8 y;
  __builtin_memcpy(&y, &t, 16);
  return y;
}

__device__ __forceinline__ bf16x8 cvt8(float4 a, float4 b) {
  bf16x8 v;
  v[0] = (bf16_t)a.x; v[1] = (bf16_t)a.y; v[2] = (bf16_t)a.z; v[3] = (bf16_t)a.w;
  v[4] = (bf16_t)b.x; v[5] = (bf16_t)b.y; v[6] = (bf16_t)b.z; v[7] = (bf16_t)b.w;
  return v;
}

// ---------------- prep: f32 -> bf16 ----------------
#define ITEM_S (SZ / 8)
#define ITEM_N (NN / 8)

__global__ __launch_bounds__(256) void prep6_kernel(
    const float* __restrict__ u, const float* __restrict__ w,
    const float* __restrict__ G, const float* __restrict__ Bm,
    const float* __restrict__ Wp, const float* __restrict__ Wq,
    bf16_t* __restrict__ ws) {
  size_t stride = (size_t)gridDim.x * blockDim.x;
  const size_t tot = 2 * ITEM_S + 4 * ITEM_N;
  for (size_t i = (size_t)blockIdx.x * blockDim.x + threadIdx.x; i < tot;
       i += stride) {
    const float* src;
    bf16_t* dst;
    size_t off;
    if (i < ITEM_S) { src = u; dst = ws; off = i; }
    else if (i < 2 * ITEM_S) { src = w; dst = ws + SZ; off = i - ITEM_S; }
    else if (i < 2 * ITEM_S + ITEM_N) { src = G; dst = ws + 2 * SZ; off = i - 2 * ITEM_S; }
    else if (i < 2 * ITEM_S + 2 * ITEM_N) { src = Bm; dst = ws + 2 * SZ + NN; off = i - 2 * ITEM_S - ITEM_N; }
    else if (i < 2 * ITEM_S + 3 * ITEM_N) { src = Wp; dst = ws + 2 * SZ + 2 * NN; off = i - 2 * ITEM_S - 2 * ITEM_N; }
    else { src = Wq; dst = ws + 2 * SZ + 3 * NN; off = i - 2 * ITEM_S - 3 * ITEM_N; }
    const float4* s = reinterpret_cast<const float4*>(src) + off * 2;
    reinterpret_cast<bf16x8*>(dst)[off] = cvt8(s[0], s[1]);
  }
}

__global__ __launch_bounds__(256) void prep4_kernel(
    const float* __restrict__ u, const float* __restrict__ w,
    const float* __restrict__ G, const float* __restrict__ Bm,
    bf16_t* __restrict__ ws) {
  size_t stride = (size_t)gridDim.x * blockDim.x;
  const size_t tot = 2 * ITEM_S + 2 * ITEM_N;
  for (size_t i = (size_t)blockIdx.x * blockDim.x + threadIdx.x; i < tot;
       i += stride) {
    const float* src;
    bf16_t* dst;
    size_t off;
    if (i < ITEM_S) { src = u; dst = ws; off = i; }
    else if (i < 2 * ITEM_S) { src = w; dst = ws + SZ; off = i - ITEM_S; }
    else if (i < 2 * ITEM_S + ITEM_N) { src = G; dst = ws + 2 * SZ; off = i - 2 * ITEM_S; }
    else { src = Bm; dst = ws + 2 * SZ + NN; off = i - 2 * ITEM_S - ITEM_N; }
    const float4* s = reinterpret_cast<const float4*>(src) + off * 2;
    reinterpret_cast<bf16x8*>(dst)[off] = cvt8(s[0], s[1]);
  }
}

// ---------------- fused stage 1: v6 (ledger best, 133.7us) ----------------
// S = u@G^T - w@B^T, T = w@G^T + u@B^T; p_mid/q_mid epilogue (bf16).
// Tile 128x128, 8 waves (2m x 4n, wave 64x32), ring-4 (128 KB).
// Per wave per half: 12 ds_read_b128 + 4 gload_lds + 32 MFMA, one
// {counted vmcnt; barrier}.
__global__ __launch_bounds__(512, 2) void fused1_v6(
    const float* __restrict__ u, const float* __restrict__ w,
    const bf16_t* __restrict__ ubf, const bf16_t* __restrict__ wbf,
    const bf16_t* __restrict__ Gbf, const bf16_t* __restrict__ Bbf,
    const float* __restrict__ bias_p, const float* __restrict__ bias_q,
    bf16_t* __restrict__ pq) {
  __shared__ bf16_t lds[4][4][128 * 32];  // [slot][op][row*32] = 128 KB
  const int tid = threadIdx.x, lane = tid & 63, wv = tid >> 6;
  const int bid = blockIdx.x;
  const int t = (bid & 7) * 32 + (bid >> 3);  // XCD swizzle, 256 blocks
  const int row0 = (t & 7) * 128, col0 = (t >> 3) * 128;
  const int wm = (wv >> 2) * 64, wn = (wv & 3) * 32;
  const int lr = lane & 15, kq = lane >> 4;
  const int kswz = (kq ^ ((lr >> 1) & 3)) << 3;

  const int srow = wv * 16 + (lane >> 2);
  const int sc = (lane & 3) ^ ((lane >> 3) & 3);
  const bf16_t* gsrc[4];
  gsrc[0] = ubf + (size_t)(row0 + srow) * NB + sc * 8;
  gsrc[1] = wbf + (size_t)(row0 + srow) * NB + sc * 8;
  gsrc[2] = Gbf + (size_t)(col0 + srow) * NB + sc * 8;
  gsrc[3] = Bbf + (size_t)(col0 + srow) * NB + sc * 8;

#define F1_ISS(op, sl, ko) GLOAD16(gsrc[op] + (ko), &lds[sl][op][wv * 512])

  int aoff[4], boff[2];
#pragma unroll
  for (int m = 0; m < 4; ++m) aoff[m] = (wm + m * 16 + lr) * 32 + kswz;
#pragma unroll
  for (int n = 0; n < 2; ++n) boff[n] = (wn + n * 16 + lr) * 32 + kswz;

  f32x4 aS[4][2] = {}, aT[4][2] = {};

  // prologue: issue halves 0,1,2
#pragma unroll
  for (int hh = 0; hh < 3; ++hh) {
    F1_ISS(0, hh, hh * 32);
    F1_ISS(1, hh, hh * 32);
    F1_ISS(2, hh, hh * 32);
    F1_ISS(3, hh, hh * 32);
  }
  VMCNT(8);  // half 0 landed
  SBAR();
  SCHEDB();

  const int HTOT = 2 * (NB / 64);  // 128 halves
  for (int h = 0; h < HTOT; ++h) {
    const int slot = h & 3;
    const bool pf = (h + 3) < HTOT;
    const int pslot = (h + 3) & 3;
    const int pko = (h + 3) * 32;

    bf16x8 bG[2], bB[2], au[4], aw[4];
#pragma unroll
    for (int n = 0; n < 2; ++n) {
      bG[n] = *reinterpret_cast<const bf16x8*>(&lds[slot][2][boff[n]]);
      bB[n] = *reinterpret_cast<const bf16x8*>(&lds[slot][3][boff[n]]);
    }
#pragma unroll
    for (int m = 0; m < 4; ++m) {
      au[m] = *reinterpret_cast<const bf16x8*>(&lds[slot][0][aoff[m]]);
      aw[m] = *reinterpret_cast<const bf16x8*>(&lds[slot][1][aoff[m]]);
    }
    if (pf) {
      F1_ISS(0, pslot, pko);
      F1_ISS(1, pslot, pko);
      F1_ISS(2, pslot, pko);
      F1_ISS(3, pslot, pko);
    }
    bf16x8 bBn[2] = {neg8(bB[0]), neg8(bB[1])};
#pragma unroll
    for (int m = 0; m < 4; ++m)
#pragma unroll
      for (int n = 0; n < 2; ++n) {
        aS[m][n] = MFMA16(au[m], bG[n], aS[m][n]);
        aS[m][n] = MFMA16(aw[m], bBn[n], aS[m][n]);
        aT[m][n] = MFMA16(aw[m], bG[n], aT[m][n]);
        aT[m][n] = MFMA16(au[m], bB[n], aT[m][n]);
      }
    // one counted sync per half
    if (h < HTOT - 3)
      VMCNT(8);
    else if (h == HTOT - 3)
      VMCNT(4);
    else if (h == HTOT - 2)
      VMCNT(0);
    SBAR();
    SCHEDB();
  }

  // epilogue: combine with u,w (f32) + biases -> p_mid/q_mid bf16
  const int fr = lane & 15, fq = kq;
#pragma unroll
  for (int m = 0; m < 4; ++m)
#pragma unroll
    for (int n = 0; n < 2; ++n)
#pragma unroll
      for (int j = 0; j < 4; ++j) {
        int r = row0 + wm + m * 16 + fq * 4 + j;
        int c = col0 + wn + n * 16 + fr;
        size_t idx = (size_t)r * NB + c;
        float U = u[idx], W = w[idx];
        float S = aS[m][n][j], T = aT[m][n][j];
        pq[idx] = (bf16_t)(U * S + W * T + bias_p[c]);
        pq[SZ + idx] = (bf16_t)(W * S - U * T + bias_q[c]);
      }
}

// ---------------- stage 2: gemm2_v9 (ledger best) ----------------
// out_z = pq_z @ W_z^T + b_z (f32). Tile 128x128, 4 waves (2x2, wave 64x64),
// ring-4 (64 KB -> 2 blocks/CU). Per half/wave: 8 ds_read + 4 gload_lds +
// 16 MFMA, one {counted vmcnt; barrier}. Grid 512, XCD-swizzled, parity koff.
__global__ __launch_bounds__(256, 2) void gemm2_v9(
    const bf16_t* __restrict__ pq, const bf16_t* __restrict__ Wpb,
    const bf16_t* __restrict__ Wqb, const float* __restrict__ bp,
    const float* __restrict__ bq, float* __restrict__ out) {
  __shared__ bf16_t lds[4][2][128 * 32];  // [slot][A/W] = 64 KB
  const int tid = threadIdx.x, lane = tid & 63, wv = tid >> 6;
  const int bid = blockIdx.x;
  const int t = (bid & 7) * 64 + (bid >> 3);  // XCD swizzle, 512 blocks
  const int z = t >> 8;
  const int s = t & 255;
  const int row0 = (s & 7) * 128, col0 = (s >> 3) * 128;
  const int koff = (bid & 1) << 6;

  const bf16_t* A = pq + (size_t)z * SZ;
  const bf16_t* Wm = z ? Wqb : Wpb;
  const float* bias = z ? bq : bp;
  float* C = out + (size_t)z * SZ;

  const int wm = (wv >> 1) * 64, wn = (wv & 1) * 64;
  const int lr = lane & 15, kq = lane >> 4;
  const int kswz = (kq ^ ((lr >> 1) & 3)) << 3;

  const int srow = tid >> 2;  // 0..63
  const int sc = (tid & 3) ^ ((tid >> 3) & 3);
  const bf16_t* gA0 = A + (size_t)(row0 + srow) * NB + sc * 8;
  const bf16_t* gA1 = gA0 + (size_t)64 * NB;
  const bf16_t* gW0 = Wm + (size_t)(col0 + srow) * NB + sc * 8;
  const bf16_t* gW1 = gW0 + (size_t)64 * NB;

#define G2_ISSUE(hh)                                                           \
  do {                                                                         \
    const int _sl = (hh) & 3;                                                  \
    const int _ko = (((hh) + koff) & 127) * 32;                                \
    GLOAD16(gA0 + _ko, &lds[_sl][0][wv * 512]);                                \
    GLOAD16(gA1 + _ko, &lds[_sl][0][2048 + wv * 512]);                         \
    GLOAD16(gW0 + _ko, &lds[_sl][1][wv * 512]);                                \
    GLOAD16(gW1 + _ko, &lds[_sl][1][2048 + wv * 512]);                         \
  } while (0)

  int aoff[4], woff[4];
#pragma unroll
  for (int m = 0; m < 4; ++m) aoff[m] = (wm + m * 16 + lr) * 32 + kswz;
#pragma unroll
  for (int n = 0; n < 4; ++n) woff[n] = (wn + n * 16 + lr) * 32 + kswz;

  f32x4 acc[4][4] = {};

  G2_ISSUE(0); G2_ISSUE(1); G2_ISSUE(2);
  VMCNT(4);
  SBAR();
  SCHEDB();

  const int HTOT = 2 * (NB / 64);
  for (int h = 0; h < HTOT; ++h) {
    const int slot = h & 3;
    const bool pf = (h + 3) < HTOT;

    bf16x8 av[4], bw[4];
#pragma unroll
    for (int m = 0; m < 4; ++m)
      av[m] = *reinterpret_cast<const bf16x8*>(&lds[slot][0][aoff[m]]);
#pragma unroll
    for (int n = 0; n < 4; ++n)
      bw[n] = *reinterpret_cast<const bf16x8*>(&lds[slot][1][woff[n]]);
    if (pf) G2_ISSUE(h + 3);
#pragma unroll
    for (int m = 0; m < 4; ++m)
#pragma unroll
      for (int n = 0; n < 4; ++n)
        acc[m][n] = MFMA16(av[m], bw[n], acc[m][n]);
    if (h < HTOT - 3)
      VMCNT(4);
    else if (h == HTOT - 3)
      VMCNT(2);
    else if (h == HTOT - 2)
      VMCNT(0);
    SBAR();
    SCHEDB();
  }

  const int fr = lane & 15, fq = kq;
#pragma unroll
  for (int m = 0; m < 4; ++m)
#pragma unroll
    for (int n = 0; n < 4; ++n)
#pragma unroll
      for (int j = 0; j < 4; ++j) {
        int r = row0 + wm + m * 16 + fq * 4 + j;
        int c = col0 + wn + n * 16 + fr;
        C[(size_t)r * NB + c] = acc[m][n][j] + bias[c];
      }
}

// ---------------- fallbacks (compile-only safety net) ----------------
__device__ __forceinline__ int swz_off32(int r, int kk) {
  return r * 32 + ((kk ^ ((r >> 1) & 3)) << 3);
}

__device__ __forceinline__ void fb_stage_f32(const float* __restrict__ src,
                                             int row0, int k0, bf16_t* lds, int t) {
  int r = t >> 2, kk = t & 3;
  const float* p = src + (size_t)(row0 + r) * NB + k0 + (kk << 3);
  float4 v0 = *reinterpret_cast<const float4*>(p);
  float4 v1 = *reinterpret_cast<const float4*>(p + 4);
  *reinterpret_cast<bf16x8*>(lds + swz_off32(r, kk)) = cvt8(v0, v1);
}

__global__ __launch_bounds__(256, 2) void fb_gemm2(
    const bf16_t* __restrict__ pq, const float* __restrict__ Wp,
    const float* __restrict__ Wq, const float* __restrict__ bp,
    const float* __restrict__ bq, float* __restrict__ out) {
  __shared__ bf16_t lA[128 * 32], lW[128 * 32];
  const int z = blockIdx.z;
  const bf16_t* A = pq + (size_t)z * SZ;
  const float* Wm = z ? Wq : Wp;
  const float* bias = z ? bq : bp;
  float* C = out + (size_t)z * SZ;
  const int tid = threadIdx.x;
  const int lane = tid & 63, wv = tid >> 6;
  const int wm = (wv >> 1) * 64, wn = (wv & 1) * 64;
  const int row0 = blockIdx.y * 128, col0 = blockIdx.x * 128;
  const int lr = lane & 15, kq = lane >> 4;
  const int fslot = (kq ^ ((lr >> 1) & 3)) << 3;
  f32x4 acc[4][4] = {};
  for (int kt = 0; kt < NB; kt += 32) {
#pragma unroll
    for (int p = 0; p < 2; ++p) {
      int cb = p * 256 + wv * 64;
      int ci = cb + lane;
      int r = ci >> 2, kl = ci & 3;
      int ks = kl ^ ((r >> 1) & 3);
      const bf16_t* g = A + (size_t)(row0 + r) * NB + kt + (ks << 3);
      GLOAD16(g, lA + cb * 8);
    }
#pragma unroll
    for (int p = 0; p < 2; ++p)
      fb_stage_f32(Wm, col0, kt, lW, p * 256 + tid);
    __syncthreads();
    bf16x8 af[4], bg[4];
#pragma unroll
    for (int m = 0; m < 4; ++m)
      af[m] = *reinterpret_cast<const bf16x8*>(lA + (wm + m * 16 + lr) * 32 + fslot);
#pragma unroll
    for (int n = 0; n < 4; ++n)
      bg[n] = *reinterpret_cast<const bf16x8*>(lW + (wn + n * 16 + lr) * 32 + fslot);
#pragma unroll
    for (int m = 0; m < 4; ++m)
#pragma unroll
      for (int n = 0; n < 4; ++n)
        acc[m][n] = MFMA16(af[m], bg[n], acc[m][n]);
    __syncthreads();
  }
  const int fr = lane & 15, fq = lane >> 4;
#pragma unroll
  for (int m = 0; m < 4; ++m)
#pragma unroll
    for (int n = 0; n < 4; ++n)
#pragma unroll
      for (int j = 0; j < 4; ++j) {
        int r = row0 + wm + m * 16 + fq * 4 + j;
        int c = col0 + wn + n * 16 + fr;
        C[(size_t)r * NB + c] = acc[m][n][j] + bias[c];
      }
}

__global__ __launch_bounds__(512, 2) void fb_fused1(
    const float* __restrict__ u, const float* __restrict__ w,
    const float* __restrict__ G, const float* __restrict__ Bm,
    const float* __restrict__ bias_p, const float* __restrict__ bias_q,
    bf16_t* __restrict__ pq) {
  __shared__ bf16_t lU[128 * 32], lW[128 * 32], lG[128 * 32], lB[128 * 32];
  const int tid = threadIdx.x;
  const int lane = tid & 63, wv = tid >> 6;
  const int wm = (wv >> 2) * 64, wn = (wv & 3) * 32;
  const int row0 = blockIdx.y * 128, col0 = blockIdx.x * 128;
  const int lr = lane & 15, kq = lane >> 4;
  const int fslot = (kq ^ ((lr >> 1) & 3)) << 3;
  f32x4 aS[4][2] = {}, aT[4][2] = {};
  for (int kt = 0; kt < NB; kt += 32) {
    fb_stage_f32(u, row0, kt, lU, tid);
    fb_stage_f32(w, row0, kt, lW, tid);
    fb_stage_f32(G, col0, kt, lG, tid);
    fb_stage_f32(Bm, col0, kt, lB, tid);
    __syncthreads();
    bf16x8 au[4], aw[4], bG[2], bB[2], bBn[2];
#pragma unroll
    for (int m = 0; m < 4; ++m) {
      int off = (wm + m * 16 + lr) * 32 + fslot;
      au[m] = *reinterpret_cast<const bf16x8*>(lU + off);
      aw[m] = *reinterpret_cast<const bf16x8*>(lW + off);
    }
#pragma unroll
    for (int n = 0; n < 2; ++n) {
      int off = (wn + n * 16 + lr) * 32 + fslot;
      bG[n] = *reinterpret_cast<const bf16x8*>(lG + off);
      bB[n] = *reinterpret_cast<const bf16x8*>(lB + off);
      bBn[n] = neg8(bB[n]);
    }
#pragma unroll
    for (int m = 0; m < 4; ++m)
#pragma unroll
      for (int n = 0; n < 2; ++n) {
        aS[m][n] = MFMA16(au[m], bG[n], aS[m][n]);
        aS[m][n] = MFMA16(aw[m], bBn[n], aS[m][n]);
        aT[m][n] = MFMA16(aw[m], bG[n], aT[m][n]);
        aT[m][n] = MFMA16(au[m], bB[n], aT[m][n]);
      }
    __syncthreads();
  }
  const int fr = lane & 15, fq = lane >> 4;
#pragma unroll
  for (int m = 0; m < 4; ++m)
#pragma unroll
    for (int n = 0; n < 2; ++n)
#pragma unroll
      for (int j = 0; j < 4; ++j) {
        int r = row0 + wm + m * 16 + fq * 4 + j;
        int c = col0 + wn + n * 16 + fr;
        size_t idx = (size_t)r * NB + c;
        float U = u[idx], W = w[idx];
        float S = aS[m][n][j], T = aT[m][n][j];
        pq[idx] = (bf16_t)(U * S + W * T + bias_p[c]);
        pq[SZ + idx] = (bf16_t)(W * S - U * T + bias_q[c]);
      }
}

extern "C" void kernel_launch(void* const* d_in, const int* in_sizes, int n_in,
                              void* d_out, int out_size, void* d_ws, size_t ws_size,
                              hipStream_t stream) {
  const float* u = (const float*)d_in[0];
  const float* w = (const float*)d_in[1];
  const float* G = (const float*)d_in[2];
  const float* Bm = (const float*)d_in[3];
  const float* bias_p = (const float*)d_in[4];
  const float* bias_q = (const float*)d_in[5];
  const float* Wp = (const float*)d_in[6];
  const float* bp = (const float*)d_in[7];
  const float* Wq = (const float*)d_in[8];
  const float* bq = (const float*)d_in[9];
  (void)in_sizes; (void)n_in; (void)out_size;

  const size_t need_full = (6 * SZ + 4 * NN) * sizeof(bf16_t);  // 176 MB
  const size_t need_mid = (6 * SZ + 2 * NN) * sizeof(bf16_t);   // 112 MB

  if (ws_size >= need_full) {
    bf16_t* ws = (bf16_t*)d_ws;
    bf16_t* ubf = ws;
    bf16_t* wbf = ws + SZ;
    bf16_t* Gbf = ws + 2 * SZ;
    bf16_t* Bbf = Gbf + NN;
    bf16_t* Wpb = Bbf + NN;
    bf16_t* Wqb = Wpb + NN;
    bf16_t* pqw = Wqb + NN;
    prep6_kernel<<<2048, 256, 0, stream>>>(u, w, G, Bm, Wp, Wq, ws);
    fused1_v6<<<256, 512, 0, stream>>>(u, w, ubf, wbf, Gbf, Bbf,
                                       bias_p, bias_q, pqw);
    gemm2_v9<<<512, 256, 0, stream>>>(pqw, Wpb, Wqb, bp, bq, (float*)d_out);
  } else if (ws_size >= need_mid) {
    bf16_t* ws = (bf16_t*)d_ws;
    bf16_t* ubf = ws;
    bf16_t* wbf = ws + SZ;
    bf16_t* Gbf = ws + 2 * SZ;
    bf16_t* Bbf = Gbf + NN;
    bf16_t* pqw = Bbf + NN;
    prep4_kernel<<<2048, 256, 0, stream>>>(u, w, G, Bm, ws);
    fused1_v6<<<256, 512, 0, stream>>>(u, w, ubf, wbf, Gbf, Bbf,
                                       bias_p, bias_q, pqw);
    fb_gemm2<<<dim3(NB / 128, MB / 128, 2), 256, 0, stream>>>(
        pqw, Wp, Wq, bp, bq, (float*)d_out);
  } else {
    bf16_t* pqw = (bf16_t*)d_ws;
    fb_fused1<<<dim3(NB / 128, MB / 128), 512, 0, stream>>>(
        u, w, G, Bm, bias_p, bias_q, pqw);
    fb_gemm2<<<dim3(NB / 128, MB / 128, 2), 256, 0, stream>>>(
        pqw, Wp, Wq, bp, bq, (float*)d_out);
  }
}